// Round 22
// baseline (265.217 us; speedup 1.0000x reference)
//
#include <hip/hip_runtime.h>
#include <hip/hip_bf16.h>
#include <math.h>

#define NB 8
#define CIN 128
#define CDN 64
#define NPIX 16384            // 128*128
#define NHEADS 8
#define HDIM 8

typedef __attribute__((ext_vector_type(8))) short bf16x8;
typedef __attribute__((ext_vector_type(4))) float f32x4;
typedef __attribute__((ext_vector_type(8))) unsigned short u16x8;

struct alignas(8) c2 { float x, y; };

__device__ inline c2 cadd(c2 a, c2 b){ return {a.x+b.x, a.y+b.y}; }
__device__ inline c2 csub(c2 a, c2 b){ return {a.x-b.x, a.y-b.y}; }
__device__ inline c2 cmul(c2 a, c2 b){ return {a.x*b.x - a.y*b.y, a.x*b.y + a.y*b.x}; }
__device__ inline c2 shfl2(c2 v, int m){ return { __shfl_xor(v.x, m, 64), __shfl_xor(v.y, m, 64) }; }
__device__ inline float gelu_exact(float v){ return 0.5f*v*(1.f + erff(v*0.70710678118654752f)); }
__device__ inline unsigned short f2bf(float f){
  __hip_bfloat16 h = __float2bfloat16(f);
  return *reinterpret_cast<unsigned short*>(&h);
}
__device__ inline float bf2f(unsigned short u){ return __uint_as_float((unsigned)u << 16); }

// ---- twiddle-hoisted 128-pt wave FFT: lane t holds positions t and t+64 ----
struct Tw { c2 t0; c2 t[6]; };
__device__ inline void tw_init(Tw& w, int t){
  float sn, cs;
  sincosf(-6.283185307179586f * (float)t * (1.f/128.f), &sn, &cs); w.t0 = {cs, sn};
  #pragma unroll
  for (int i = 0; i < 6; ++i) {
    int sp = 32 >> i;
    int j = t & (sp-1);
    sincosf(-3.141592653589793f * (float)j / (float)sp, &sn, &cs);
    w.t[i] = {cs, sn};
  }
}
// forward DIF: natural in -> slot order out. Lane t reg a <-> freq 2*br6(t); reg b <-> 2*br6(t)+1.
__device__ inline void fft128_fwd(c2& a, c2& b, int t, const Tw& w){
  c2 s = cadd(a,b), d = csub(a,b);
  a = s; b = cmul(d, w.t0);
  #pragma unroll
  for (int i = 0; i < 6; ++i) {
    int sp = 32 >> i;
    c2 oa = shfl2(a, sp), ob = shfl2(b, sp);
    c2 tw = w.t[i];
    if (t & sp) { a = cmul(csub(oa,a), tw); b = cmul(csub(ob,b), tw); }
    else        { a = cadd(a,oa);           b = cadd(b,ob); }
  }
}
// inverse DIT (no scaling): slot order in -> natural out
__device__ inline void fft128_inv(c2& a, c2& b, int t, const Tw& w){
  #pragma unroll
  for (int i = 5; i >= 0; --i) {
    int sp = 32 >> i;
    c2 tw = {w.t[i].x, -w.t[i].y};
    c2 oa = shfl2(a, sp), ob = shfl2(b, sp);
    if (t & sp) { a = csub(oa, cmul(a, tw)); b = csub(ob, cmul(b, tw)); }
    else        { a = cadd(a, cmul(oa, tw)); b = cadd(b, cmul(ob, tw)); }
  }
  c2 t0c = {w.t0.x, -w.t0.y};
  c2 wb = cmul(b, t0c);
  b = csub(a, wb);
  a = cadd(a, wb);
}

__device__ inline void gload_lds16(const void* g, void* l){
  __builtin_amdgcn_global_load_lds(
      (const __attribute__((address_space(1))) unsigned int*)g,
      (__attribute__((address_space(3))) unsigned int*)l, 16, 0, 0);
}

// sigma-closed 4-column sets, pass A (cols 0..63). Pairing: (idx0,idx3),(idx1,idx2);
// wv0 special: cols 0,1 are sigma-fixed (DC/Nyquist of the dyadic map).
__device__ inline int cmapA(int wv, int i){
  if (wv == 0) return i;                        // {0,1,2,3}
  if (wv == 1) return 4 + i;                    // {4,5,6,7}
  if (wv == 2) return i < 2 ? 8 + i : 12 + i;   // {8,9,14,15}
  if (wv == 3) return 10 + i;                   // {10,11,12,13}
  if (wv < 8) { int a = wv - 4; return i < 2 ? 16 + 2*a + i : 28 - 2*a + i; }
  int a = wv - 8; return i < 2 ? 32 + 2*a + i : 60 - 2*a + i;
}
// pass B (cols 64..127, stored at col-64). sigma(s)=191-s; set {2w,2w+1,62-2w,63-2w}+64.
__device__ inline int cmapB(int wv, int i){
  return i < 2 ? 2*wv + i : 60 - 2*wv + i;
}

// Combined preprocessing: blocks [0,512): x -> xT bf16 [b][4cc][pix][32ci];
// blocks [512,800): conv_w -> wPack bf16 [cc=4][tap=9][co=64][ci=32].
__global__ __launch_bounds__(256) void k_prep(const float* __restrict__ x, unsigned short* __restrict__ xT,
                                              const float* __restrict__ w, unsigned short* __restrict__ wP){
  if (blockIdx.x < 512) {
    int b = blockIdx.x >> 6;
    int px = (blockIdx.x & 63)*256 + threadIdx.x;
    const float* xb = x + (size_t)b*CIN*NPIX + px;
    #pragma unroll 2
    for (int ci0 = 0; ci0 < 128; ci0 += 8) {
      u16x8 v;
      #pragma unroll
      for (int j = 0; j < 8; ++j) v[j] = f2bf(xb[(size_t)(ci0+j)*NPIX]);
      int cc = ci0 >> 5;
      *(u16x8*)(xT + (((size_t)(b*4+cc)*NPIX + px)*32 + (ci0 & 31))) = v;
    }
  } else {
    int idx = (blockIdx.x - 512)*256 + threadIdx.x;
    if (idx >= 4*9*64*32) return;
    int cc  = idx / 18432;
    int r   = idx - cc*18432;
    int tap = r / 2048;
    int r2  = r - tap*2048;
    int co  = r2 >> 5;
    int cil = r2 & 31;
    int ci  = cc*32 + cil;
    wP[idx] = f2bf(w[(co*CIN + ci)*9 + tap]);
  }
}

// Dilated 3x3 conv + BN + exact GELU via bf16 MFMA implicit GEMM.
// co split in half per block; XCD-pairing swizzle (halves differ by 8 -> same XCD L2).
__global__ __launch_bounds__(256) void k_conv(const unsigned short* __restrict__ xT,
    const unsigned short* __restrict__ wP,
    const float* __restrict__ bg, const float* __restrict__ bbeta,
    const float* __restrict__ bm, const float* __restrict__ bv,
    const float* __restrict__ w1,
    unsigned short* __restrict__ feat, float* __restrict__ u){
  __shared__ __align__(16) unsigned short sX[512*32];   // 32,768 B: 512px x 32ci
  __shared__ float w1s[256];
  const int tid = threadIdx.x;
  const int flat = blockIdx.x + (blockIdx.y << 4) + (blockIdx.z << 7);  // grid (16,8,8)
  const int half = (flat >> 3) & 1;
  const int tf   = (flat & 7) | ((flat >> 4) << 3);    // tile id in [0,512)
  const int x0 = (tf & 7) * 16;
  const int y0 = ((tf >> 3) & 7) * 16;
  const int bb = tf >> 6;
  const int coBase = half*32;
  const int wv  = tid >> 6;
  const int l   = tid & 63;
  const int l15 = l & 15;
  const int g   = l >> 4;

  w1s[tid] = w1[tid];

  const bool interior = (x0 >= 16) && (x0 <= 96) && (y0 >= 16) && (y0 <= 96);

  f32x4 acc[2][4];
  #pragma unroll
  for (int m=0;m<2;++m)
    #pragma unroll
    for (int n=0;n<4;++n) acc[m][n] = {0.f,0.f,0.f,0.f};

  const int ko = g*8;                 // K-offset within 32-ci chunk (granule g)

  for (int cc = 0; cc < 4; ++cc) {
    __syncthreads();
    const unsigned short* xcc = xT + ((size_t)(bb*4 + cc))*NPIX*32;
    if (interior) {
      #pragma unroll
      for (int k = 0; k < 8; ++k) {
        int blk = k*4 + wv;            // 64-granule block, wave-uniform
        int idx = blk*64 + l;          // granule id
        int p = idx >> 2, i = idx & 3;
        int pc = p < 484 ? p : 483;
        int py = pc / 22, px = pc - py*22;
        int gpix = (y0-3+py)*128 + (x0-3+px);
        int sg = i ^ ((p >> 1) & 3);
        const unsigned short* srcp = xcc + (size_t)gpix*32 + sg*8;
        gload_lds16(srcp, (char*)sX + blk*1024);
      }
    } else {
      #pragma unroll
      for (int k = 0; k < 8; ++k) {
        int idx = k*256 + tid;
        int p = idx >> 2, i = idx & 3;
        u16x8 v = {0,0,0,0,0,0,0,0};
        if (p < 484) {
          int py = p / 22, px = p - py*22;
          int gy = y0-3+py, gx = x0-3+px;
          if ((unsigned)gy < 128u && (unsigned)gx < 128u) {
            int sg = i ^ ((p >> 1) & 3);
            v = *(const u16x8*)(xcc + (size_t)(gy*128+gx)*32 + sg*8);
          }
        }
        *(u16x8*)((char*)sX + idx*16) = v;
      }
    }
    __syncthreads();

    const unsigned short* wcc = wP + cc*18432;
    for (int tap = 0; tap < 9; ++tap) {
      int dy = (tap/3)*3, dx = (tap - (tap/3)*3)*3;
      const unsigned short* wt = wcc + tap*2048;
      bf16x8 a[2], b[4];
      #pragma unroll
      for (int m = 0; m < 2; ++m)
        a[m] = *reinterpret_cast<const bf16x8*>(wt + (coBase + m*16 + l15)*32 + ko);
      #pragma unroll
      for (int n = 0; n < 4; ++n) {
        int p = (wv*4 + n + dy)*22 + l15 + dx;
        b[n] = *reinterpret_cast<const bf16x8*>(&sX[p*32 + ((g ^ ((p >> 1) & 3)) << 3)]);
      }
      #pragma unroll
      for (int m = 0; m < 2; ++m)
        #pragma unroll
        for (int n = 0; n < 4; ++n)
          acc[m][n] = __builtin_amdgcn_mfma_f32_16x16x32_bf16(a[m], b[n], acc[m][n], 0, 0, 0);
    }
  }

  // epilogue: BN + GELU + feat store (bf16) + fused u partials (this half's 32 couts)
  float up[4][4];   // [n][m2]
  #pragma unroll
  for (int n=0;n<4;++n)
    #pragma unroll
    for (int m2=0;m2<4;++m2) up[n][m2] = 0.f;

  #pragma unroll
  for (int m = 0; m < 2; ++m) {
    #pragma unroll
    for (int r = 0; r < 4; ++r) {
      int co = coBase + m*16 + g*4 + r;
      float sc = bg[co] * rsqrtf(bv[co] + 1e-5f);
      float sh = bbeta[co] - bm[co]*sc;
      float wv4[4];
      #pragma unroll
      for (int m2 = 0; m2 < 4; ++m2) wv4[m2] = w1s[m2*64 + co];
      #pragma unroll
      for (int n = 0; n < 4; ++n) {
        int py = wv*4 + n;
        float v = gelu_exact(acc[m][n][r]*sc + sh);
        feat[((size_t)(bb*CDN + co)*128 + (y0+py))*128 + x0 + l15] = f2bf(v);
        #pragma unroll
        for (int m2 = 0; m2 < 4; ++m2) up[n][m2] += wv4[m2]*v;
      }
    }
  }
  #pragma unroll
  for (int n=0;n<4;++n)
    #pragma unroll
    for (int m2=0;m2<4;++m2) {
      up[n][m2] += __shfl_xor(up[n][m2], 16, 64);
      up[n][m2] += __shfl_xor(up[n][m2], 32, 64);
    }
  if (g == 0) {
    #pragma unroll
    for (int n = 0; n < 4; ++n) {
      int py = y0 + wv*4 + n;
      #pragma unroll
      for (int m2 = 0; m2 < 4; ++m2)
        u[((size_t)((bb*2 + half)*4 + m2))*NPIX + py*128 + x0 + l15] = up[n][m2];
    }
  }
}

// Mid-pipeline combo (512 threads):
//   blocks [0,512):   attn1 partial Gram (feat-dependent)
//   blocks [512,544): ufft 2-D FFT of u -> mid (u-dependent; only 32 blocks, fills idle CUs)
__global__ __launch_bounds__(512) void k_mid(const unsigned short* __restrict__ feat, float* __restrict__ part,
    const float* __restrict__ u, const float* __restrict__ b1,
    const float* __restrict__ gg, const float* __restrict__ gbeta,
    const float* __restrict__ gm, const float* __restrict__ gv,
    float* __restrict__ mid){
  __shared__ c2 T[64*129];   // 66,048 B (attn1 path reuses as float scratch)
  int tid = threadIdx.x, wv = tid >> 6, t = tid & 63;

  if (blockIdx.x < 512) {
    // ---------------- attn1 path ----------------
    int bh = blockIdx.x >> 3, ck = blockIdx.x & 7;
    int b = bh >> 3, h = bh & 7;
    const unsigned short* f = feat + (size_t)(b*CDN + h*HDIM)*NPIX;
    float acc[36];
    #pragma unroll
    for (int i=0;i<36;++i) acc[i]=0.f;
    for (int p = ck*2048 + tid; p < (ck+1)*2048; p += 512) {
      float v[8];
      #pragma unroll
      for (int d=0; d<8; ++d) v[d] = bf2f(f[d*NPIX + p]);
      int i = 0;
      #pragma unroll
      for (int d=0; d<8; ++d)
        #pragma unroll
        for (int e=0; e<=d; ++e) acc[i++] += v[d]*v[e];
    }
    #pragma unroll
    for (int i=0;i<36;++i)
      #pragma unroll
      for (int off=32; off; off>>=1) acc[i] += __shfl_xor(acc[i], off, 64);
    float* red = (float*)T;    // [8][36]
    if (t == 0) {
      #pragma unroll
      for (int i=0;i<36;++i) red[wv*36 + i] = acc[i];
    }
    __syncthreads();
    if (tid < 36) {
      float s = 0.f;
      #pragma unroll
      for (int k = 0; k < 8; ++k) s += red[k*36 + tid];
      part[(bh*8+ck)*36 + tid] = s;
    }
    return;
  }

  // ---------------- ufft path ----------------
  int ib = blockIdx.x - 512;       // [0,32)
  int b = ib >> 2, m = ib & 3;
  Tw w; tw_init(w, t);
  const float* src0 = u + (size_t)((b*2+0)*4+m)*NPIX;
  const float* src1 = u + (size_t)((b*2+1)*4+m)*NPIX;
  c2 ra[16], rb[16];
  #pragma unroll
  for (int i = 0; i < 16; ++i) {
    int y = wv*16 + i;
    ra[i] = {src0[y*128 + t] + src1[y*128 + t], 0.f};
    rb[i] = {src0[y*128 + t + 64] + src1[y*128 + t + 64], 0.f};
  }
  #pragma unroll
  for (int i = 0; i < 16; ++i) fft128_fwd(ra[i], rb[i], t, w);
  c2 ca[16], cb[16];
  if (wv < 4) {
    #pragma unroll
    for (int i = 0; i < 16; ++i) {
      int y = wv*16 + i;
      T[y*129 + t] = ra[i]; T[y*129 + t + 64] = rb[i];
    }
  }
  __syncthreads();
  #pragma unroll
  for (int i = 0; i < 16; ++i) ca[i] = T[t*129 + wv*16 + i];
  __syncthreads();
  if (wv >= 4) {
    #pragma unroll
    for (int i = 0; i < 16; ++i) {
      int y = (wv-4)*16 + i;
      T[y*129 + t] = ra[i]; T[y*129 + t + 64] = rb[i];
    }
  }
  __syncthreads();
  #pragma unroll
  for (int i = 0; i < 16; ++i) cb[i] = T[t*129 + wv*16 + i];
  #pragma unroll
  for (int i = 0; i < 16; ++i) fft128_fwd(ca[i], cb[i], t, w);
  float sc = gg[m]*rsqrtf(gv[m]+1e-5f);
  float sh = gbeta[m] - gm[m]*sc;
  float bb1 = b1[m];
  float* md = mid + (size_t)(b*4+m)*NPIX;
  #pragma unroll
  for (int i = 0; i < 16; ++i) {
    int kx = wv*16 + i;
    md[kx*128 + t]      = gelu_exact((ca[i].x + bb1)*sc + sh);
    md[kx*128 + t + 64] = gelu_exact((cb[i].x + bb1)*sc + sh);
  }
}

// gPack[b][cp][k] = bf16(sigmoid gate ch=cp) | bf16(sigmoid gate ch=cp+32)<<16
__global__ __launch_bounds__(1024) void k_gmap(const float* __restrict__ mid, const float* __restrict__ w2,
                                               const float* __restrict__ b2, unsigned* __restrict__ gPack){
  __shared__ float S[320];
  int tid = threadIdx.x;
  if (tid < 256) S[tid] = w2[tid];
  else if (tid < 320) S[tid] = b2[tid - 256];
  __syncthreads();
  int b = blockIdx.x >> 4;
  int k = (blockIdx.x & 15)*1024 + tid;
  const float* md = mid + (size_t)b*4*NPIX + k;
  float m0 = md[0], m1 = md[NPIX], m2 = md[2*NPIX], m3 = md[3*NPIX];
  unsigned* gp = gPack + (size_t)b*32*NPIX + k;
  #pragma unroll 8
  for (int cp = 0; cp < 32; ++cp) {
    float slo = S[256+cp]    + S[cp*4]*m0      + S[cp*4+1]*m1      + S[cp*4+2]*m2      + S[cp*4+3]*m3;
    float shi = S[256+cp+32] + S[(cp+32)*4]*m0 + S[(cp+32)*4+1]*m1 + S[(cp+32)*4+2]*m2 + S[(cp+32)*4+3]*m3;
    slo = 1.f/(1.f+expf(-slo));
    shi = 1.f/(1.f+expf(-shi));
    gp[(size_t)cp*NPIX] = ((unsigned)f2bf(shi) << 16) | (unsigned)f2bf(slo);
  }
}

// Final merged kernel, 512 blocks x 1024 threads (exactly 2 blocks/CU):
//   blocks [0,256):   Hermitian-packed fused gate branch (DS/VALU-bound, 66.5KB LDS)
//   blocks [256,512): outf attention epilogue, 4096 px/block (HBM-bound)
// One block of each type per CU: outf's memory waits fill fused's DS gaps
// (R20's 1024 outf blocks oversubscribed and regressed; this pairs 1:1).
__global__ __launch_bounds__(1024)
void k_last(const unsigned short* __restrict__ feat, const unsigned* __restrict__ gPack,
            const float* __restrict__ part, const float* __restrict__ tau,
            const float* __restrict__ x, float* __restrict__ out){
  __shared__ c2 T[128*65];   // 66,560 B
  int tid = threadIdx.x, wv = tid >> 6, t = tid & 63;

  if (blockIdx.x >= 256) {
    // ---------------- outf path: 4096 pixels per block ----------------
    int idx = blockIdx.x - 256;      // [0,256)
    int bh = idx >> 2, q = idx & 3;
    int b = bh >> 3, h = bh & 7;
    float* S = (float*)T;            // A[64]; Gm at S[64..100)
    if (tid < 36) {
      float s = 0.f;
      #pragma unroll
      for (int k = 0; k < 8; ++k) s += part[(bh*8+k)*36 + tid];
      S[64 + tid] = s;
    }
    __syncthreads();
    if (tid == 0) {
      float G[8][8];
      int c2i=0;
      for (int d=0;d<8;++d) for(int e=0;e<=d;++e){
        float s = S[64 + c2i]; G[d][e]=s; G[e][d]=s; ++c2i;
      }
      float nrm[8];
      for (int d=0;d<8;++d) nrm[d] = sqrtf(16384.f*G[d][d] + 1e-6f);
      float tv = tau[h];
      for (int d=0;d<8;++d) {
        float row[8]; float mx = -1e30f;
        for (int e=0;e<8;++e){ row[e] = tv*16384.f*G[d][e]/(nrm[d]*nrm[e]); mx = fmaxf(mx,row[e]); }
        float s=0.f;
        for (int e=0;e<8;++e){ row[e] = expf(row[e]-mx); s += row[e]; }
        for (int e=0;e<8;++e) S[d*8+e] = row[e]/s;
      }
    }
    __syncthreads();
    const unsigned short* f = feat + (size_t)(b*CDN + h*HDIM)*NPIX;
    #pragma unroll
    for (int it = 0; it < 4; ++it) {
      int p = q*4096 + it*1024 + tid;
      float v[8];
      #pragma unroll
      for (int e=0;e<8;++e) v[e] = bf2f(f[e*NPIX + p]);
      float im = 0.f;
      #pragma unroll
      for (int e=0;e<8;++e) im += v[e];
      im *= 0.125f;
      #pragma unroll
      for (int d=0;d<8;++d){
        float re = 0.f;
        #pragma unroll
        for (int e=0;e<8;++e) re += S[d*8+e]*v[e];
        size_t o = ((size_t)(b*CIN + h*HDIM + d))*NPIX + p;
        out[o] = sqrtf(re*re + im*im) + x[o];
      }
    }
    return;
  }

  // ---------------- fused gate-branch path ----------------
  int ib = blockIdx.x;       // b*32 + c, c in [0,32)
  int b = ib >> 5, c = ib & 31;
  Tw w; tw_init(w, t);
  int ta = __brev((64 - (__brev(t) >> 26)) & 63) >> 26;   // ky-partner lane for a-slots
  const unsigned short* srcA = feat + (size_t)(b*CDN + c)*NPIX;
  const unsigned short* srcB = feat + (size_t)(b*CDN + c + 32)*NPIX;
  const unsigned* gp = gPack + (size_t)(b*32 + c)*NPIX;

  c2 ra[8], rb[8];
  #pragma unroll
  for (int i = 0; i < 8; ++i) {
    int y = wv*8 + i;
    ra[i] = {bf2f(srcA[y*128 + t]),      bf2f(srcB[y*128 + t])};
    rb[i] = {bf2f(srcA[y*128 + t + 64]), bf2f(srcB[y*128 + t + 64])};
  }
  #pragma unroll
  for (int i = 0; i < 8; ++i) fft128_fwd(ra[i], rb[i], t, w);

  #define GUN(w_, lo_, hi_) float lo_ = __uint_as_float((w_) << 16); float hi_ = __uint_as_float((w_) & 0xffff0000u);
  #define CPAIR(I, J) { \
    GUN(gwa[I], g1aI, g2aI); GUN(gwb[I], g1bI, g2bI); \
    GUN(gwa[J], g1aJ, g2aJ); GUN(gwb[J], g1bJ, g2bJ); \
    c2 paI = { __shfl(ca[J].x, ta, 64), -__shfl(ca[J].y, ta, 64) }; \
    c2 paJ = { __shfl(ca[I].x, ta, 64), -__shfl(ca[I].y, ta, 64) }; \
    c2 pbI = { __shfl_xor(cb[J].x, 63, 64), -__shfl_xor(cb[J].y, 63, 64) }; \
    c2 pbJ = { __shfl_xor(cb[I].x, 63, 64), -__shfl_xor(cb[I].y, 63, 64) }; \
    float gsaI=0.5f*(g1aI+g2aI), gdaI=0.5f*(g1aI-g2aI); \
    float gsaJ=0.5f*(g1aJ+g2aJ), gdaJ=0.5f*(g1aJ-g2aJ); \
    float gsbI=0.5f*(g1bI+g2bI), gdbI=0.5f*(g1bI-g2bI); \
    float gsbJ=0.5f*(g1bJ+g2bJ), gdbJ=0.5f*(g1bJ-g2bJ); \
    ca[I] = { gsaI*ca[I].x + gdaI*paI.x, gsaI*ca[I].y + gdaI*paI.y }; \
    ca[J] = { gsaJ*ca[J].x + gdaJ*paJ.x, gsaJ*ca[J].y + gdaJ*paJ.y }; \
    cb[I] = { gsbI*cb[I].x + gdbI*pbI.x, gsbI*cb[I].y + gdbI*pbI.y }; \
    cb[J] = { gsbJ*cb[J].x + gdbJ*pbJ.x, gsbJ*cb[J].y + gdbJ*pbJ.y }; \
  }
  #define CSELF(I) { \
    GUN(gwa[I], g1aI, g2aI); GUN(gwb[I], g1bI, g2bI); \
    c2 paI = { __shfl(ca[I].x, ta, 64), -__shfl(ca[I].y, ta, 64) }; \
    c2 pbI = { __shfl_xor(cb[I].x, 63, 64), -__shfl_xor(cb[I].y, 63, 64) }; \
    float gsaI=0.5f*(g1aI+g2aI), gdaI=0.5f*(g1aI-g2aI); \
    float gsbI=0.5f*(g1bI+g2bI), gdbI=0.5f*(g1bI-g2bI); \
    ca[I] = { gsaI*ca[I].x + gdaI*paI.x, gsaI*ca[I].y + gdaI*paI.y }; \
    cb[I] = { gsbI*cb[I].x + gdbI*pbI.x, gsbI*cb[I].y + gdbI*pbI.y }; \
  }

  // ---- PASS A: columns 0..63 ----
  #pragma unroll
  for (int i = 0; i < 8; ++i) T[(wv*8 + i)*65 + t] = ra[i];
  __syncthreads();
  {
    int s0 = cmapA(wv,0), s1 = cmapA(wv,1), s2 = cmapA(wv,2), s3 = cmapA(wv,3);
    c2 ca[4], cb[4];
    ca[0]=T[t*65+s0]; ca[1]=T[t*65+s1]; ca[2]=T[t*65+s2]; ca[3]=T[t*65+s3];
    cb[0]=T[(t+64)*65+s0]; cb[1]=T[(t+64)*65+s1]; cb[2]=T[(t+64)*65+s2]; cb[3]=T[(t+64)*65+s3];
    unsigned gwa[4], gwb[4];
    gwa[0]=gp[s0*128+t]; gwa[1]=gp[s1*128+t]; gwa[2]=gp[s2*128+t]; gwa[3]=gp[s3*128+t];
    gwb[0]=gp[s0*128+64+t]; gwb[1]=gp[s1*128+64+t]; gwb[2]=gp[s2*128+64+t]; gwb[3]=gp[s3*128+64+t];
    #pragma unroll
    for (int j = 0; j < 4; ++j) fft128_fwd(ca[j], cb[j], t, w);
    if (wv == 0) { CSELF(0); CSELF(1); CPAIR(2,3); }
    else         { CPAIR(0,3); CPAIR(1,2); }
    #pragma unroll
    for (int j = 0; j < 4; ++j) fft128_inv(ca[j], cb[j], t, w);
    __syncthreads();
    T[t*65+s0]=ca[0]; T[t*65+s1]=ca[1]; T[t*65+s2]=ca[2]; T[t*65+s3]=ca[3];
    T[(t+64)*65+s0]=cb[0]; T[(t+64)*65+s1]=cb[1]; T[(t+64)*65+s2]=cb[2]; T[(t+64)*65+s3]=cb[3];
  }
  __syncthreads();
  #pragma unroll
  for (int i = 0; i < 8; ++i) ra[i] = T[(wv*8 + i)*65 + t];
  __syncthreads();

  // ---- PASS B: columns 64..127 (stored at col-64) ----
  #pragma unroll
  for (int i = 0; i < 8; ++i) T[(wv*8 + i)*65 + t] = rb[i];
  __syncthreads();
  {
    int s0 = cmapB(wv,0), s1 = cmapB(wv,1), s2 = cmapB(wv,2), s3 = cmapB(wv,3);
    c2 ca[4], cb[4];
    ca[0]=T[t*65+s0]; ca[1]=T[t*65+s1]; ca[2]=T[t*65+s2]; ca[3]=T[t*65+s3];
    cb[0]=T[(t+64)*65+s0]; cb[1]=T[(t+64)*65+s1]; cb[2]=T[(t+64)*65+s2]; cb[3]=T[(t+64)*65+s3];
    unsigned gwa[4], gwb[4];
    gwa[0]=gp[(64+s0)*128+t]; gwa[1]=gp[(64+s1)*128+t]; gwa[2]=gp[(64+s2)*128+t]; gwa[3]=gp[(64+s3)*128+t];
    gwb[0]=gp[(64+s0)*128+64+t]; gwb[1]=gp[(64+s1)*128+64+t]; gwb[2]=gp[(64+s2)*128+64+t]; gwb[3]=gp[(64+s3)*128+64+t];
    #pragma unroll
    for (int j = 0; j < 4; ++j) fft128_fwd(ca[j], cb[j], t, w);
    CPAIR(0,3); CPAIR(1,2);
    #pragma unroll
    for (int j = 0; j < 4; ++j) fft128_inv(ca[j], cb[j], t, w);
    __syncthreads();
    T[t*65+s0]=ca[0]; T[t*65+s1]=ca[1]; T[t*65+s2]=ca[2]; T[t*65+s3]=ca[3];
    T[(t+64)*65+s0]=cb[0]; T[(t+64)*65+s1]=cb[1]; T[(t+64)*65+s2]=cb[2]; T[(t+64)*65+s3]=cb[3];
  }
  __syncthreads();
  #pragma unroll
  for (int i = 0; i < 8; ++i) rb[i] = T[(wv*8 + i)*65 + t];
  #undef CPAIR
  #undef CSELF
  #undef GUN

  // inverse row FFT + abs + residual (out1 = Re -> ch 64+c, out2 = Im -> ch 96+c)
  #pragma unroll
  for (int i = 0; i < 8; ++i) fft128_inv(ra[i], rb[i], t, w);
  const float* xr1 = x + ((size_t)(b*CIN + 64 + c))*NPIX;
  const float* xr2 = x + ((size_t)(b*CIN + 96 + c))*NPIX;
  float* o1 = out + ((size_t)(b*CIN + 64 + c))*NPIX;
  float* o2 = out + ((size_t)(b*CIN + 96 + c))*NPIX;
  const float s = 1.f/16384.f;
  #pragma unroll
  for (int i = 0; i < 8; ++i) {
    int y = wv*8 + i;
    o1[y*128 + t]      = fabsf(ra[i].x)*s + xr1[y*128 + t];
    o1[y*128 + t + 64] = fabsf(rb[i].x)*s + xr1[y*128 + t + 64];
    o2[y*128 + t]      = fabsf(ra[i].y)*s + xr2[y*128 + t];
    o2[y*128 + t + 64] = fabsf(rb[i].y)*s + xr2[y*128 + t + 64];
  }
}

extern "C" void kernel_launch(void* const* d_in, const int* in_sizes, int n_in,
                              void* d_out, int out_size, void* d_ws, size_t ws_size,
                              hipStream_t stream){
  const float* x      = (const float*)d_in[0];
  const float* conv_w = (const float*)d_in[1];
  const float* bn1_g  = (const float*)d_in[2];
  const float* bn1_b  = (const float*)d_in[3];
  const float* bn1_m  = (const float*)d_in[4];
  const float* bn1_v  = (const float*)d_in[5];
  const float* cg1_w  = (const float*)d_in[6];
  const float* cg1_b  = (const float*)d_in[7];
  const float* cgbn_g = (const float*)d_in[8];
  const float* cgbn_b = (const float*)d_in[9];
  const float* cgbn_m = (const float*)d_in[10];
  const float* cgbn_v = (const float*)d_in[11];
  const float* cg2_w  = (const float*)d_in[12];
  const float* cg2_b  = (const float*)d_in[13];
  const float* tau    = (const float*)d_in[14];
  float* out = (float*)d_out;

  char* ws = (char*)d_ws;
  unsigned short* feat  = (unsigned short*)ws;                  // 16,777,216 B (bf16)
  unsigned short* xT    = (unsigned short*)(ws + 33554432);     // 33,554,432 B (dead after k_conv)
  unsigned*       gPack = (unsigned*)(ws + 33554432);           // 16,777,216 B, aliases xT (safe)
  float*          u     = (float*)(ws + 67108864);              // 4,194,304 B ([b][half][m][NPIX])
  float*          mid   = (float*)(ws + 71303168);              // 2,097,152 B
  unsigned short* wPack = (unsigned short*)(ws + 73400320);     // 147,456 B
  float*          part  = (float*)(ws + 73547776);              // 73,728 B

  k_prep<<<800, 256, 0, stream>>>(x, xT, conv_w, wPack);
  k_conv<<<dim3(16,8,NB), 256, 0, stream>>>(xT, wPack, bn1_g, bn1_b, bn1_m, bn1_v, cg1_w, feat, u);
  k_mid<<<544, 512, 0, stream>>>(feat, part, u, cg1_b, cgbn_g, cgbn_b, cgbn_m, cgbn_v, mid);
  k_gmap<<<128, 1024, 0, stream>>>(mid, cg2_w, cg2_b, gPack);
  k_last<<<512, 1024, 0, stream>>>(feat, gPack, part, tau, x, out);
}

// Round 23
// 198.929 us; speedup vs baseline: 1.3332x; 1.3332x over previous
//
#include <hip/hip_runtime.h>
#include <hip/hip_bf16.h>
#include <math.h>

#define NB 8
#define CIN 128
#define CDN 64
#define NPIX 16384            // 128*128
#define NHEADS 8
#define HDIM 8

typedef __attribute__((ext_vector_type(8))) short bf16x8;
typedef __attribute__((ext_vector_type(4))) float f32x4;
typedef __attribute__((ext_vector_type(8))) unsigned short u16x8;

struct alignas(8) c2 { float x, y; };

__device__ inline c2 cadd(c2 a, c2 b){ return {a.x+b.x, a.y+b.y}; }
__device__ inline c2 csub(c2 a, c2 b){ return {a.x-b.x, a.y-b.y}; }
__device__ inline c2 cmul(c2 a, c2 b){ return {a.x*b.x - a.y*b.y, a.x*b.y + a.y*b.x}; }
__device__ inline c2 shfl2(c2 v, int m){ return { __shfl_xor(v.x, m, 64), __shfl_xor(v.y, m, 64) }; }
__device__ inline float gelu_exact(float v){ return 0.5f*v*(1.f + erff(v*0.70710678118654752f)); }
__device__ inline unsigned short f2bf(float f){
  __hip_bfloat16 h = __float2bfloat16(f);
  return *reinterpret_cast<unsigned short*>(&h);
}
__device__ inline float bf2f(unsigned short u){ return __uint_as_float((unsigned)u << 16); }

// ---- twiddle-hoisted 128-pt wave FFT: lane t holds positions t and t+64 ----
struct Tw { c2 t0; c2 t[6]; };
__device__ inline void tw_init(Tw& w, int t){
  float sn, cs;
  sincosf(-6.283185307179586f * (float)t * (1.f/128.f), &sn, &cs); w.t0 = {cs, sn};
  #pragma unroll
  for (int i = 0; i < 6; ++i) {
    int sp = 32 >> i;
    int j = t & (sp-1);
    sincosf(-3.141592653589793f * (float)j / (float)sp, &sn, &cs);
    w.t[i] = {cs, sn};
  }
}
// forward DIF: natural in -> slot order out. Lane t reg a <-> freq 2*br6(t); reg b <-> 2*br6(t)+1.
__device__ inline void fft128_fwd(c2& a, c2& b, int t, const Tw& w){
  c2 s = cadd(a,b), d = csub(a,b);
  a = s; b = cmul(d, w.t0);
  #pragma unroll
  for (int i = 0; i < 6; ++i) {
    int sp = 32 >> i;
    c2 oa = shfl2(a, sp), ob = shfl2(b, sp);
    c2 tw = w.t[i];
    if (t & sp) { a = cmul(csub(oa,a), tw); b = cmul(csub(ob,b), tw); }
    else        { a = cadd(a,oa);           b = cadd(b,ob); }
  }
}
// inverse DIT (no scaling): slot order in -> natural out
__device__ inline void fft128_inv(c2& a, c2& b, int t, const Tw& w){
  #pragma unroll
  for (int i = 5; i >= 0; --i) {
    int sp = 32 >> i;
    c2 tw = {w.t[i].x, -w.t[i].y};
    c2 oa = shfl2(a, sp), ob = shfl2(b, sp);
    if (t & sp) { a = csub(oa, cmul(a, tw)); b = csub(ob, cmul(b, tw)); }
    else        { a = cadd(a, cmul(oa, tw)); b = cadd(b, cmul(ob, tw)); }
  }
  c2 t0c = {w.t0.x, -w.t0.y};
  c2 wb = cmul(b, t0c);
  b = csub(a, wb);
  a = cadd(a, wb);
}

__device__ inline void gload_lds16(const void* g, void* l){
  __builtin_amdgcn_global_load_lds(
      (const __attribute__((address_space(1))) unsigned int*)g,
      (__attribute__((address_space(3))) unsigned int*)l, 16, 0, 0);
}

// sigma-closed 4-column sets, pass A (cols 0..63). Pairing: (idx0,idx3),(idx1,idx2);
// wv0 special: cols 0,1 are sigma-fixed (DC/Nyquist of the dyadic map).
__device__ inline int cmapA(int wv, int i){
  if (wv == 0) return i;                        // {0,1,2,3}
  if (wv == 1) return 4 + i;                    // {4,5,6,7}
  if (wv == 2) return i < 2 ? 8 + i : 12 + i;   // {8,9,14,15}
  if (wv == 3) return 10 + i;                   // {10,11,12,13}
  if (wv < 8) { int a = wv - 4; return i < 2 ? 16 + 2*a + i : 28 - 2*a + i; }
  int a = wv - 8; return i < 2 ? 32 + 2*a + i : 60 - 2*a + i;
}
// pass B (cols 64..127, stored at col-64). sigma(s)=191-s; set {2w,2w+1,62-2w,63-2w}+64.
__device__ inline int cmapB(int wv, int i){
  return i < 2 ? 2*wv + i : 60 - 2*wv + i;
}

// Combined preprocessing: blocks [0,512): x -> xT bf16 [b][4cc][pix][32ci];
// blocks [512,800): conv_w -> wPack bf16 [cc=4][tap=9][co=64][ci=32].
__global__ __launch_bounds__(256) void k_prep(const float* __restrict__ x, unsigned short* __restrict__ xT,
                                              const float* __restrict__ w, unsigned short* __restrict__ wP){
  if (blockIdx.x < 512) {
    int b = blockIdx.x >> 6;
    int px = (blockIdx.x & 63)*256 + threadIdx.x;
    const float* xb = x + (size_t)b*CIN*NPIX + px;
    #pragma unroll 2
    for (int ci0 = 0; ci0 < 128; ci0 += 8) {
      u16x8 v;
      #pragma unroll
      for (int j = 0; j < 8; ++j) v[j] = f2bf(xb[(size_t)(ci0+j)*NPIX]);
      int cc = ci0 >> 5;
      *(u16x8*)(xT + (((size_t)(b*4+cc)*NPIX + px)*32 + (ci0 & 31))) = v;
    }
  } else {
    int idx = (blockIdx.x - 512)*256 + threadIdx.x;
    if (idx >= 4*9*64*32) return;
    int cc  = idx / 18432;
    int r   = idx - cc*18432;
    int tap = r / 2048;
    int r2  = r - tap*2048;
    int co  = r2 >> 5;
    int cil = r2 & 31;
    int ci  = cc*32 + cil;
    wP[idx] = f2bf(w[(co*CIN + ci)*9 + tap]);
  }
}

// Dilated 3x3 conv + BN + exact GELU via bf16 MFMA implicit GEMM.
// co split in half per block; XCD-pairing swizzle (halves differ by 8 -> same XCD L2).
__global__ __launch_bounds__(256) void k_conv(const unsigned short* __restrict__ xT,
    const unsigned short* __restrict__ wP,
    const float* __restrict__ bg, const float* __restrict__ bbeta,
    const float* __restrict__ bm, const float* __restrict__ bv,
    const float* __restrict__ w1,
    unsigned short* __restrict__ feat, float* __restrict__ u){
  __shared__ __align__(16) unsigned short sX[512*32];   // 32,768 B: 512px x 32ci
  __shared__ float w1s[256];
  const int tid = threadIdx.x;
  const int flat = blockIdx.x + (blockIdx.y << 4) + (blockIdx.z << 7);  // grid (16,8,8)
  const int half = (flat >> 3) & 1;
  const int tf   = (flat & 7) | ((flat >> 4) << 3);    // tile id in [0,512)
  const int x0 = (tf & 7) * 16;
  const int y0 = ((tf >> 3) & 7) * 16;
  const int bb = tf >> 6;
  const int coBase = half*32;
  const int wv  = tid >> 6;
  const int l   = tid & 63;
  const int l15 = l & 15;
  const int g   = l >> 4;

  w1s[tid] = w1[tid];

  const bool interior = (x0 >= 16) && (x0 <= 96) && (y0 >= 16) && (y0 <= 96);

  f32x4 acc[2][4];
  #pragma unroll
  for (int m=0;m<2;++m)
    #pragma unroll
    for (int n=0;n<4;++n) acc[m][n] = {0.f,0.f,0.f,0.f};

  const int ko = g*8;                 // K-offset within 32-ci chunk (granule g)

  for (int cc = 0; cc < 4; ++cc) {
    __syncthreads();
    const unsigned short* xcc = xT + ((size_t)(bb*4 + cc))*NPIX*32;
    if (interior) {
      #pragma unroll
      for (int k = 0; k < 8; ++k) {
        int blk = k*4 + wv;            // 64-granule block, wave-uniform
        int idx = blk*64 + l;          // granule id
        int p = idx >> 2, i = idx & 3;
        int pc = p < 484 ? p : 483;
        int py = pc / 22, px = pc - py*22;
        int gpix = (y0-3+py)*128 + (x0-3+px);
        int sg = i ^ ((p >> 1) & 3);
        const unsigned short* srcp = xcc + (size_t)gpix*32 + sg*8;
        gload_lds16(srcp, (char*)sX + blk*1024);
      }
    } else {
      #pragma unroll
      for (int k = 0; k < 8; ++k) {
        int idx = k*256 + tid;
        int p = idx >> 2, i = idx & 3;
        u16x8 v = {0,0,0,0,0,0,0,0};
        if (p < 484) {
          int py = p / 22, px = p - py*22;
          int gy = y0-3+py, gx = x0-3+px;
          if ((unsigned)gy < 128u && (unsigned)gx < 128u) {
            int sg = i ^ ((p >> 1) & 3);
            v = *(const u16x8*)(xcc + (size_t)(gy*128+gx)*32 + sg*8);
          }
        }
        *(u16x8*)((char*)sX + idx*16) = v;
      }
    }
    __syncthreads();

    const unsigned short* wcc = wP + cc*18432;
    for (int tap = 0; tap < 9; ++tap) {
      int dy = (tap/3)*3, dx = (tap - (tap/3)*3)*3;
      const unsigned short* wt = wcc + tap*2048;
      bf16x8 a[2], b[4];
      #pragma unroll
      for (int m = 0; m < 2; ++m)
        a[m] = *reinterpret_cast<const bf16x8*>(wt + (coBase + m*16 + l15)*32 + ko);
      #pragma unroll
      for (int n = 0; n < 4; ++n) {
        int p = (wv*4 + n + dy)*22 + l15 + dx;
        b[n] = *reinterpret_cast<const bf16x8*>(&sX[p*32 + ((g ^ ((p >> 1) & 3)) << 3)]);
      }
      #pragma unroll
      for (int m = 0; m < 2; ++m)
        #pragma unroll
        for (int n = 0; n < 4; ++n)
          acc[m][n] = __builtin_amdgcn_mfma_f32_16x16x32_bf16(a[m], b[n], acc[m][n], 0, 0, 0);
    }
  }

  // epilogue: BN + GELU + feat store (bf16) + fused u partials (this half's 32 couts)
  float up[4][4];   // [n][m2]
  #pragma unroll
  for (int n=0;n<4;++n)
    #pragma unroll
    for (int m2=0;m2<4;++m2) up[n][m2] = 0.f;

  #pragma unroll
  for (int m = 0; m < 2; ++m) {
    #pragma unroll
    for (int r = 0; r < 4; ++r) {
      int co = coBase + m*16 + g*4 + r;
      float sc = bg[co] * rsqrtf(bv[co] + 1e-5f);
      float sh = bbeta[co] - bm[co]*sc;
      float wv4[4];
      #pragma unroll
      for (int m2 = 0; m2 < 4; ++m2) wv4[m2] = w1s[m2*64 + co];
      #pragma unroll
      for (int n = 0; n < 4; ++n) {
        int py = wv*4 + n;
        float v = gelu_exact(acc[m][n][r]*sc + sh);
        feat[((size_t)(bb*CDN + co)*128 + (y0+py))*128 + x0 + l15] = f2bf(v);
        #pragma unroll
        for (int m2 = 0; m2 < 4; ++m2) up[n][m2] += wv4[m2]*v;
      }
    }
  }
  #pragma unroll
  for (int n=0;n<4;++n)
    #pragma unroll
    for (int m2=0;m2<4;++m2) {
      up[n][m2] += __shfl_xor(up[n][m2], 16, 64);
      up[n][m2] += __shfl_xor(up[n][m2], 32, 64);
    }
  if (g == 0) {
    #pragma unroll
    for (int n = 0; n < 4; ++n) {
      int py = y0 + wv*4 + n;
      #pragma unroll
      for (int m2 = 0; m2 < 4; ++m2)
        u[((size_t)((bb*2 + half)*4 + m2))*NPIX + py*128 + x0 + l15] = up[n][m2];
    }
  }
}

// Mid-pipeline combo (512 threads):
//   blocks [0,512):   attn1 partial Gram (feat-dependent)
//   blocks [512,544): ufft 2-D FFT of u -> mid (u-dependent; only 32 blocks, fills idle CUs)
__global__ __launch_bounds__(512) void k_mid(const unsigned short* __restrict__ feat, float* __restrict__ part,
    const float* __restrict__ u, const float* __restrict__ b1,
    const float* __restrict__ gg, const float* __restrict__ gbeta,
    const float* __restrict__ gm, const float* __restrict__ gv,
    float* __restrict__ mid){
  __shared__ c2 T[64*129];   // 66,048 B (attn1 path reuses as float scratch)
  int tid = threadIdx.x, wv = tid >> 6, t = tid & 63;

  if (blockIdx.x < 512) {
    // ---------------- attn1 path ----------------
    int bh = blockIdx.x >> 3, ck = blockIdx.x & 7;
    int b = bh >> 3, h = bh & 7;
    const unsigned short* f = feat + (size_t)(b*CDN + h*HDIM)*NPIX;
    float acc[36];
    #pragma unroll
    for (int i=0;i<36;++i) acc[i]=0.f;
    for (int p = ck*2048 + tid; p < (ck+1)*2048; p += 512) {
      float v[8];
      #pragma unroll
      for (int d=0; d<8; ++d) v[d] = bf2f(f[d*NPIX + p]);
      int i = 0;
      #pragma unroll
      for (int d=0; d<8; ++d)
        #pragma unroll
        for (int e=0; e<=d; ++e) acc[i++] += v[d]*v[e];
    }
    #pragma unroll
    for (int i=0;i<36;++i)
      #pragma unroll
      for (int off=32; off; off>>=1) acc[i] += __shfl_xor(acc[i], off, 64);
    float* red = (float*)T;    // [8][36]
    if (t == 0) {
      #pragma unroll
      for (int i=0;i<36;++i) red[wv*36 + i] = acc[i];
    }
    __syncthreads();
    if (tid < 36) {
      float s = 0.f;
      #pragma unroll
      for (int k = 0; k < 8; ++k) s += red[k*36 + tid];
      part[(bh*8+ck)*36 + tid] = s;
    }
    return;
  }

  // ---------------- ufft path ----------------
  int ib = blockIdx.x - 512;       // [0,32)
  int b = ib >> 2, m = ib & 3;
  Tw w; tw_init(w, t);
  const float* src0 = u + (size_t)((b*2+0)*4+m)*NPIX;
  const float* src1 = u + (size_t)((b*2+1)*4+m)*NPIX;
  c2 ra[16], rb[16];
  #pragma unroll
  for (int i = 0; i < 16; ++i) {
    int y = wv*16 + i;
    ra[i] = {src0[y*128 + t] + src1[y*128 + t], 0.f};
    rb[i] = {src0[y*128 + t + 64] + src1[y*128 + t + 64], 0.f};
  }
  #pragma unroll
  for (int i = 0; i < 16; ++i) fft128_fwd(ra[i], rb[i], t, w);
  c2 ca[16], cb[16];
  if (wv < 4) {
    #pragma unroll
    for (int i = 0; i < 16; ++i) {
      int y = wv*16 + i;
      T[y*129 + t] = ra[i]; T[y*129 + t + 64] = rb[i];
    }
  }
  __syncthreads();
  #pragma unroll
  for (int i = 0; i < 16; ++i) ca[i] = T[t*129 + wv*16 + i];
  __syncthreads();
  if (wv >= 4) {
    #pragma unroll
    for (int i = 0; i < 16; ++i) {
      int y = (wv-4)*16 + i;
      T[y*129 + t] = ra[i]; T[y*129 + t + 64] = rb[i];
    }
  }
  __syncthreads();
  #pragma unroll
  for (int i = 0; i < 16; ++i) cb[i] = T[t*129 + wv*16 + i];
  #pragma unroll
  for (int i = 0; i < 16; ++i) fft128_fwd(ca[i], cb[i], t, w);
  float sc = gg[m]*rsqrtf(gv[m]+1e-5f);
  float sh = gbeta[m] - gm[m]*sc;
  float bb1 = b1[m];
  float* md = mid + (size_t)(b*4+m)*NPIX;
  #pragma unroll
  for (int i = 0; i < 16; ++i) {
    int kx = wv*16 + i;
    md[kx*128 + t]      = gelu_exact((ca[i].x + bb1)*sc + sh);
    md[kx*128 + t + 64] = gelu_exact((cb[i].x + bb1)*sc + sh);
  }
}

// Tail combo (1024 threads):
//   blocks [0,128):    gmap (mid-dependent) -> gPack
//   blocks [128,1152): outf attention epilogue (part-dependent) -> out ch 0..63
__global__ __launch_bounds__(1024) void k_tail(const float* __restrict__ mid, const float* __restrict__ w2,
    const float* __restrict__ b2, unsigned* __restrict__ gPack,
    const unsigned short* __restrict__ feat, const float* __restrict__ part,
    const float* __restrict__ tau, const float* __restrict__ x, float* __restrict__ out){
  __shared__ float S[384];
  int tid = threadIdx.x;

  if (blockIdx.x < 128) {
    // ---------------- gmap path ----------------
    if (tid < 256) S[tid] = w2[tid];
    else if (tid < 320) S[tid] = b2[tid - 256];
    __syncthreads();
    int b = blockIdx.x >> 4;
    int k = (blockIdx.x & 15)*1024 + tid;
    const float* md = mid + (size_t)b*4*NPIX + k;
    float m0 = md[0], m1 = md[NPIX], m2 = md[2*NPIX], m3 = md[3*NPIX];
    unsigned* gp = gPack + (size_t)b*32*NPIX + k;
    #pragma unroll 8
    for (int cp = 0; cp < 32; ++cp) {
      float slo = S[256+cp]    + S[cp*4]*m0      + S[cp*4+1]*m1      + S[cp*4+2]*m2      + S[cp*4+3]*m3;
      float shi = S[256+cp+32] + S[(cp+32)*4]*m0 + S[(cp+32)*4+1]*m1 + S[(cp+32)*4+2]*m2 + S[(cp+32)*4+3]*m3;
      slo = 1.f/(1.f+expf(-slo));
      shi = 1.f/(1.f+expf(-shi));
      gp[(size_t)cp*NPIX] = ((unsigned)f2bf(shi) << 16) | (unsigned)f2bf(slo);
    }
    return;
  }

  // ---------------- outf path ----------------
  int idx = blockIdx.x - 128;      // [0,1024)
  int bh = idx >> 4;
  int b = bh >> 3, h = bh & 7;
  int p = (idx & 15)*1024 + tid;
  if (tid < 36) {
    float s = 0.f;
    #pragma unroll
    for (int k = 0; k < 8; ++k) s += part[(bh*8+k)*36 + tid];
    S[64 + tid] = s;
  }
  __syncthreads();
  if (tid == 0) {
    float G[8][8];
    int c2i=0;
    for (int d=0;d<8;++d) for(int e=0;e<=d;++e){
      float s = S[64 + c2i]; G[d][e]=s; G[e][d]=s; ++c2i;
    }
    float nrm[8];
    for (int d=0;d<8;++d) nrm[d] = sqrtf(16384.f*G[d][d] + 1e-6f);
    float tv = tau[h];
    for (int d=0;d<8;++d) {
      float row[8]; float mx = -1e30f;
      for (int e=0;e<8;++e){ row[e] = tv*16384.f*G[d][e]/(nrm[d]*nrm[e]); mx = fmaxf(mx,row[e]); }
      float s=0.f;
      for (int e=0;e<8;++e){ row[e] = expf(row[e]-mx); s += row[e]; }
      for (int e=0;e<8;++e) S[d*8+e] = row[e]/s;
    }
  }
  __syncthreads();
  const unsigned short* f = feat + (size_t)(b*CDN + h*HDIM)*NPIX;
  float v[8];
  #pragma unroll
  for (int e=0;e<8;++e) v[e] = bf2f(f[e*NPIX + p]);
  float im = 0.f;
  #pragma unroll
  for (int e=0;e<8;++e) im += v[e];
  im *= 0.125f;
  #pragma unroll
  for (int d=0;d<8;++d){
    float re = 0.f;
    #pragma unroll
    for (int e=0;e<8;++e) re += S[d*8+e]*v[e];
    size_t o = ((size_t)(b*CIN + h*HDIM + d))*NPIX + p;
    out[o] = sqrtf(re*re + im*im) + x[o];
  }
}

// Hermitian-packed fused gate branch, 1024 threads. Two half-image column
// passes through T[128][65] (66.5KB), sigma-closed per half.
__global__ __launch_bounds__(1024)
void k_fused(const unsigned short* __restrict__ feat, const unsigned* __restrict__ gPack,
             const float* __restrict__ x, float* __restrict__ out){
  __shared__ c2 T[128*65];   // 66,560 B
  int ib = blockIdx.x;       // b*32 + c, c in [0,32)
  int b = ib >> 5, c = ib & 31;
  int tid = threadIdx.x, wv = tid >> 6, t = tid & 63;
  Tw w; tw_init(w, t);
  int ta = __brev((64 - (__brev(t) >> 26)) & 63) >> 26;   // ky-partner lane for a-slots
  const unsigned short* srcA = feat + (size_t)(b*CDN + c)*NPIX;
  const unsigned short* srcB = feat + (size_t)(b*CDN + c + 32)*NPIX;
  const unsigned* gp = gPack + (size_t)(b*32 + c)*NPIX;

  c2 ra[8], rb[8];
  #pragma unroll
  for (int i = 0; i < 8; ++i) {
    int y = wv*8 + i;
    ra[i] = {bf2f(srcA[y*128 + t]),      bf2f(srcB[y*128 + t])};
    rb[i] = {bf2f(srcA[y*128 + t + 64]), bf2f(srcB[y*128 + t + 64])};
  }
  #pragma unroll
  for (int i = 0; i < 8; ++i) fft128_fwd(ra[i], rb[i], t, w);

  #define GUN(w_, lo_, hi_) float lo_ = __uint_as_float((w_) << 16); float hi_ = __uint_as_float((w_) & 0xffff0000u);
  #define CPAIR(I, J) { \
    GUN(gwa[I], g1aI, g2aI); GUN(gwb[I], g1bI, g2bI); \
    GUN(gwa[J], g1aJ, g2aJ); GUN(gwb[J], g1bJ, g2bJ); \
    c2 paI = { __shfl(ca[J].x, ta, 64), -__shfl(ca[J].y, ta, 64) }; \
    c2 paJ = { __shfl(ca[I].x, ta, 64), -__shfl(ca[I].y, ta, 64) }; \
    c2 pbI = { __shfl_xor(cb[J].x, 63, 64), -__shfl_xor(cb[J].y, 63, 64) }; \
    c2 pbJ = { __shfl_xor(cb[I].x, 63, 64), -__shfl_xor(cb[I].y, 63, 64) }; \
    float gsaI=0.5f*(g1aI+g2aI), gdaI=0.5f*(g1aI-g2aI); \
    float gsaJ=0.5f*(g1aJ+g2aJ), gdaJ=0.5f*(g1aJ-g2aJ); \
    float gsbI=0.5f*(g1bI+g2bI), gdbI=0.5f*(g1bI-g2bI); \
    float gsbJ=0.5f*(g1bJ+g2bJ), gdbJ=0.5f*(g1bJ-g2bJ); \
    ca[I] = { gsaI*ca[I].x + gdaI*paI.x, gsaI*ca[I].y + gdaI*paI.y }; \
    ca[J] = { gsaJ*ca[J].x + gdaJ*paJ.x, gsaJ*ca[J].y + gdaJ*paJ.y }; \
    cb[I] = { gsbI*cb[I].x + gdbI*pbI.x, gsbI*cb[I].y + gdbI*pbI.y }; \
    cb[J] = { gsbJ*cb[J].x + gdbJ*pbJ.x, gsbJ*cb[J].y + gdbJ*pbJ.y }; \
  }
  #define CSELF(I) { \
    GUN(gwa[I], g1aI, g2aI); GUN(gwb[I], g1bI, g2bI); \
    c2 paI = { __shfl(ca[I].x, ta, 64), -__shfl(ca[I].y, ta, 64) }; \
    c2 pbI = { __shfl_xor(cb[I].x, 63, 64), -__shfl_xor(cb[I].y, 63, 64) }; \
    float gsaI=0.5f*(g1aI+g2aI), gdaI=0.5f*(g1aI-g2aI); \
    float gsbI=0.5f*(g1bI+g2bI), gdbI=0.5f*(g1bI-g2bI); \
    ca[I] = { gsaI*ca[I].x + gdaI*paI.x, gsaI*ca[I].y + gdaI*paI.y }; \
    cb[I] = { gsbI*cb[I].x + gdbI*pbI.x, gsbI*cb[I].y + gdbI*pbI.y }; \
  }

  // ---- PASS A: columns 0..63 ----
  #pragma unroll
  for (int i = 0; i < 8; ++i) T[(wv*8 + i)*65 + t] = ra[i];
  __syncthreads();
  {
    int s0 = cmapA(wv,0), s1 = cmapA(wv,1), s2 = cmapA(wv,2), s3 = cmapA(wv,3);
    c2 ca[4], cb[4];
    ca[0]=T[t*65+s0]; ca[1]=T[t*65+s1]; ca[2]=T[t*65+s2]; ca[3]=T[t*65+s3];
    cb[0]=T[(t+64)*65+s0]; cb[1]=T[(t+64)*65+s1]; cb[2]=T[(t+64)*65+s2]; cb[3]=T[(t+64)*65+s3];
    unsigned gwa[4], gwb[4];
    gwa[0]=gp[s0*128+t]; gwa[1]=gp[s1*128+t]; gwa[2]=gp[s2*128+t]; gwa[3]=gp[s3*128+t];
    gwb[0]=gp[s0*128+64+t]; gwb[1]=gp[s1*128+64+t]; gwb[2]=gp[s2*128+64+t]; gwb[3]=gp[s3*128+64+t];
    #pragma unroll
    for (int j = 0; j < 4; ++j) fft128_fwd(ca[j], cb[j], t, w);
    if (wv == 0) { CSELF(0); CSELF(1); CPAIR(2,3); }
    else         { CPAIR(0,3); CPAIR(1,2); }
    #pragma unroll
    for (int j = 0; j < 4; ++j) fft128_inv(ca[j], cb[j], t, w);
    __syncthreads();   // everyone done reading their cols before write-back
    T[t*65+s0]=ca[0]; T[t*65+s1]=ca[1]; T[t*65+s2]=ca[2]; T[t*65+s3]=ca[3];
    T[(t+64)*65+s0]=cb[0]; T[(t+64)*65+s1]=cb[1]; T[(t+64)*65+s2]=cb[2]; T[(t+64)*65+s3]=cb[3];
  }
  __syncthreads();
  #pragma unroll
  for (int i = 0; i < 8; ++i) ra[i] = T[(wv*8 + i)*65 + t];
  __syncthreads();

  // ---- PASS B: columns 64..127 (stored at col-64) ----
  #pragma unroll
  for (int i = 0; i < 8; ++i) T[(wv*8 + i)*65 + t] = rb[i];
  __syncthreads();
  {
    int s0 = cmapB(wv,0), s1 = cmapB(wv,1), s2 = cmapB(wv,2), s3 = cmapB(wv,3);
    c2 ca[4], cb[4];
    ca[0]=T[t*65+s0]; ca[1]=T[t*65+s1]; ca[2]=T[t*65+s2]; ca[3]=T[t*65+s3];
    cb[0]=T[(t+64)*65+s0]; cb[1]=T[(t+64)*65+s1]; cb[2]=T[(t+64)*65+s2]; cb[3]=T[(t+64)*65+s3];
    unsigned gwa[4], gwb[4];
    gwa[0]=gp[(64+s0)*128+t]; gwa[1]=gp[(64+s1)*128+t]; gwa[2]=gp[(64+s2)*128+t]; gwa[3]=gp[(64+s3)*128+t];
    gwb[0]=gp[(64+s0)*128+64+t]; gwb[1]=gp[(64+s1)*128+64+t]; gwb[2]=gp[(64+s2)*128+64+t]; gwb[3]=gp[(64+s3)*128+64+t];
    #pragma unroll
    for (int j = 0; j < 4; ++j) fft128_fwd(ca[j], cb[j], t, w);
    CPAIR(0,3); CPAIR(1,2);
    #pragma unroll
    for (int j = 0; j < 4; ++j) fft128_inv(ca[j], cb[j], t, w);
    __syncthreads();
    T[t*65+s0]=ca[0]; T[t*65+s1]=ca[1]; T[t*65+s2]=ca[2]; T[t*65+s3]=ca[3];
    T[(t+64)*65+s0]=cb[0]; T[(t+64)*65+s1]=cb[1]; T[(t+64)*65+s2]=cb[2]; T[(t+64)*65+s3]=cb[3];
  }
  __syncthreads();
  #pragma unroll
  for (int i = 0; i < 8; ++i) rb[i] = T[(wv*8 + i)*65 + t];
  #undef CPAIR
  #undef CSELF
  #undef GUN

  // inverse row FFT + abs + residual (out1 = Re -> ch 64+c, out2 = Im -> ch 96+c)
  #pragma unroll
  for (int i = 0; i < 8; ++i) fft128_inv(ra[i], rb[i], t, w);
  const float* xr1 = x + ((size_t)(b*CIN + 64 + c))*NPIX;
  const float* xr2 = x + ((size_t)(b*CIN + 96 + c))*NPIX;
  float* o1 = out + ((size_t)(b*CIN + 64 + c))*NPIX;
  float* o2 = out + ((size_t)(b*CIN + 96 + c))*NPIX;
  const float s = 1.f/16384.f;
  #pragma unroll
  for (int i = 0; i < 8; ++i) {
    int y = wv*8 + i;
    o1[y*128 + t]      = fabsf(ra[i].x)*s + xr1[y*128 + t];
    o1[y*128 + t + 64] = fabsf(rb[i].x)*s + xr1[y*128 + t + 64];
    o2[y*128 + t]      = fabsf(ra[i].y)*s + xr2[y*128 + t];
    o2[y*128 + t + 64] = fabsf(rb[i].y)*s + xr2[y*128 + t + 64];
  }
}

extern "C" void kernel_launch(void* const* d_in, const int* in_sizes, int n_in,
                              void* d_out, int out_size, void* d_ws, size_t ws_size,
                              hipStream_t stream){
  const float* x      = (const float*)d_in[0];
  const float* conv_w = (const float*)d_in[1];
  const float* bn1_g  = (const float*)d_in[2];
  const float* bn1_b  = (const float*)d_in[3];
  const float* bn1_m  = (const float*)d_in[4];
  const float* bn1_v  = (const float*)d_in[5];
  const float* cg1_w  = (const float*)d_in[6];
  const float* cg1_b  = (const float*)d_in[7];
  const float* cgbn_g = (const float*)d_in[8];
  const float* cgbn_b = (const float*)d_in[9];
  const float* cgbn_m = (const float*)d_in[10];
  const float* cgbn_v = (const float*)d_in[11];
  const float* cg2_w  = (const float*)d_in[12];
  const float* cg2_b  = (const float*)d_in[13];
  const float* tau    = (const float*)d_in[14];
  float* out = (float*)d_out;

  char* ws = (char*)d_ws;
  unsigned short* feat  = (unsigned short*)ws;                  // 16,777,216 B (bf16)
  unsigned short* xT    = (unsigned short*)(ws + 33554432);     // 33,554,432 B (dead after k_conv)
  unsigned*       gPack = (unsigned*)(ws + 33554432);           // 16,777,216 B, aliases xT (safe)
  float*          u     = (float*)(ws + 67108864);              // 4,194,304 B ([b][half][m][NPIX])
  float*          mid   = (float*)(ws + 71303168);              // 2,097,152 B
  unsigned short* wPack = (unsigned short*)(ws + 73400320);     // 147,456 B
  float*          part  = (float*)(ws + 73547776);              // 73,728 B

  k_prep<<<800, 256, 0, stream>>>(x, xT, conv_w, wPack);
  k_conv<<<dim3(16,8,NB), 256, 0, stream>>>(xT, wPack, bn1_g, bn1_b, bn1_m, bn1_v, cg1_w, feat, u);
  k_mid<<<544, 512, 0, stream>>>(feat, part, u, cg1_b, cgbn_g, cgbn_b, cgbn_m, cgbn_v, mid);
  k_tail<<<1152, 1024, 0, stream>>>(mid, cg2_w, cg2_b, gPack, feat, part, tau, x, out);
  k_fused<<<NB*32, 1024, 0, stream>>>(feat, gPack, x, out);
}

// Round 24
// 198.904 us; speedup vs baseline: 1.3334x; 1.0001x over previous
//
#include <hip/hip_runtime.h>
#include <hip/hip_bf16.h>
#include <math.h>

#define NB 8
#define CIN 128
#define CDN 64
#define NPIX 16384            // 128*128
#define NHEADS 8
#define HDIM 8

typedef __attribute__((ext_vector_type(8))) short bf16x8;
typedef __attribute__((ext_vector_type(4))) float f32x4;
typedef __attribute__((ext_vector_type(8))) unsigned short u16x8;

struct alignas(8) c2 { float x, y; };

__device__ inline c2 cadd(c2 a, c2 b){ return {a.x+b.x, a.y+b.y}; }
__device__ inline c2 csub(c2 a, c2 b){ return {a.x-b.x, a.y-b.y}; }
__device__ inline c2 cmul(c2 a, c2 b){ return {a.x*b.x - a.y*b.y, a.x*b.y + a.y*b.x}; }
__device__ inline c2 shfl2(c2 v, int m){ return { __shfl_xor(v.x, m, 64), __shfl_xor(v.y, m, 64) }; }
__device__ inline float gelu_exact(float v){ return 0.5f*v*(1.f + erff(v*0.70710678118654752f)); }
__device__ inline unsigned short f2bf(float f){
  __hip_bfloat16 h = __float2bfloat16(f);
  return *reinterpret_cast<unsigned short*>(&h);
}
__device__ inline float bf2f(unsigned short u){ return __uint_as_float((unsigned)u << 16); }

// ---- twiddle-hoisted 128-pt wave FFT: lane t holds positions t and t+64 ----
struct Tw { c2 t0; c2 t[6]; };
__device__ inline void tw_init(Tw& w, int t){
  float sn, cs;
  sincosf(-6.283185307179586f * (float)t * (1.f/128.f), &sn, &cs); w.t0 = {cs, sn};
  #pragma unroll
  for (int i = 0; i < 6; ++i) {
    int sp = 32 >> i;
    int j = t & (sp-1);
    sincosf(-3.141592653589793f * (float)j / (float)sp, &sn, &cs);
    w.t[i] = {cs, sn};
  }
}
// forward DIF: natural in -> slot order out. Lane t reg a <-> freq 2*br6(t); reg b <-> 2*br6(t)+1.
__device__ inline void fft128_fwd(c2& a, c2& b, int t, const Tw& w){
  c2 s = cadd(a,b), d = csub(a,b);
  a = s; b = cmul(d, w.t0);
  #pragma unroll
  for (int i = 0; i < 6; ++i) {
    int sp = 32 >> i;
    c2 oa = shfl2(a, sp), ob = shfl2(b, sp);
    c2 tw = w.t[i];
    if (t & sp) { a = cmul(csub(oa,a), tw); b = cmul(csub(ob,b), tw); }
    else        { a = cadd(a,oa);           b = cadd(b,ob); }
  }
}
// inverse DIT (no scaling): slot order in -> natural out
__device__ inline void fft128_inv(c2& a, c2& b, int t, const Tw& w){
  #pragma unroll
  for (int i = 5; i >= 0; --i) {
    int sp = 32 >> i;
    c2 tw = {w.t[i].x, -w.t[i].y};
    c2 oa = shfl2(a, sp), ob = shfl2(b, sp);
    if (t & sp) { a = csub(oa, cmul(a, tw)); b = csub(ob, cmul(b, tw)); }
    else        { a = cadd(a, cmul(oa, tw)); b = cadd(b, cmul(ob, tw)); }
  }
  c2 t0c = {w.t0.x, -w.t0.y};
  c2 wb = cmul(b, t0c);
  b = csub(a, wb);
  a = cadd(a, wb);
}

__device__ inline void gload_lds16(const void* g, void* l){
  __builtin_amdgcn_global_load_lds(
      (const __attribute__((address_space(1))) unsigned int*)g,
      (__attribute__((address_space(3))) unsigned int*)l, 16, 0, 0);
}

// sigma-closed 4-column sets, pass A (cols 0..63). Pairing: (idx0,idx3),(idx1,idx2);
// wv0 special: cols 0,1 are sigma-fixed (DC/Nyquist of the dyadic map).
__device__ inline int cmapA(int wv, int i){
  if (wv == 0) return i;                        // {0,1,2,3}
  if (wv == 1) return 4 + i;                    // {4,5,6,7}
  if (wv == 2) return i < 2 ? 8 + i : 12 + i;   // {8,9,14,15}
  if (wv == 3) return 10 + i;                   // {10,11,12,13}
  if (wv < 8) { int a = wv - 4; return i < 2 ? 16 + 2*a + i : 28 - 2*a + i; }
  int a = wv - 8; return i < 2 ? 32 + 2*a + i : 60 - 2*a + i;
}
// pass B (cols 64..127, stored at col-64). sigma(s)=191-s; set {2w,2w+1,62-2w,63-2w}+64.
__device__ inline int cmapB(int wv, int i){
  return i < 2 ? 2*wv + i : 60 - 2*wv + i;
}

// Combined preprocessing: blocks [0,512): x -> xT bf16 [b][4cc][pix][32ci];
// blocks [512,800): conv_w -> wPack bf16 [cc=4][tap=9][co=64][ci=32].
__global__ __launch_bounds__(256) void k_prep(const float* __restrict__ x, unsigned short* __restrict__ xT,
                                              const float* __restrict__ w, unsigned short* __restrict__ wP){
  if (blockIdx.x < 512) {
    int b = blockIdx.x >> 6;
    int px = (blockIdx.x & 63)*256 + threadIdx.x;
    const float* xb = x + (size_t)b*CIN*NPIX + px;
    #pragma unroll 2
    for (int ci0 = 0; ci0 < 128; ci0 += 8) {
      u16x8 v;
      #pragma unroll
      for (int j = 0; j < 8; ++j) v[j] = f2bf(xb[(size_t)(ci0+j)*NPIX]);
      int cc = ci0 >> 5;
      *(u16x8*)(xT + (((size_t)(b*4+cc)*NPIX + px)*32 + (ci0 & 31))) = v;
    }
  } else {
    int idx = (blockIdx.x - 512)*256 + threadIdx.x;
    if (idx >= 4*9*64*32) return;
    int cc  = idx / 18432;
    int r   = idx - cc*18432;
    int tap = r / 2048;
    int r2  = r - tap*2048;
    int co  = r2 >> 5;
    int cil = r2 & 31;
    int ci  = cc*32 + cil;
    wP[idx] = f2bf(w[(co*CIN + ci)*9 + tap]);
  }
}

// Dilated 3x3 conv + BN + exact GELU via bf16 MFMA implicit GEMM.
// co split in half per block; XCD-pairing swizzle (halves differ by 8 -> same XCD L2).
// All 9 taps' weight frags for a cc-chunk are loaded into registers BEFORE the
// staging barrier (aw[9][2], static indices): the per-tap L2 round-trip that
// serialized the inner loop (R23: MfmaUtil 12.5%) collapses to one latency per
// chunk, hidden under the barrier's vmcnt drain. Inner loop = ds_read + MFMA only.
__global__ __launch_bounds__(256) void k_conv(const unsigned short* __restrict__ xT,
    const unsigned short* __restrict__ wP,
    const float* __restrict__ bg, const float* __restrict__ bbeta,
    const float* __restrict__ bm, const float* __restrict__ bv,
    const float* __restrict__ w1,
    unsigned short* __restrict__ feat, float* __restrict__ u){
  __shared__ __align__(16) unsigned short sX[512*32];   // 32,768 B: 512px x 32ci
  __shared__ float w1s[256];
  const int tid = threadIdx.x;
  const int flat = blockIdx.x + (blockIdx.y << 4) + (blockIdx.z << 7);  // grid (16,8,8)
  const int half = (flat >> 3) & 1;
  const int tf   = (flat & 7) | ((flat >> 4) << 3);    // tile id in [0,512)
  const int x0 = (tf & 7) * 16;
  const int y0 = ((tf >> 3) & 7) * 16;
  const int bb = tf >> 6;
  const int coBase = half*32;
  const int wv  = tid >> 6;
  const int l   = tid & 63;
  const int l15 = l & 15;
  const int g   = l >> 4;

  w1s[tid] = w1[tid];

  const bool interior = (x0 >= 16) && (x0 <= 96) && (y0 >= 16) && (y0 <= 96);

  f32x4 acc[2][4];
  #pragma unroll
  for (int m=0;m<2;++m)
    #pragma unroll
    for (int n=0;n<4;++n) acc[m][n] = {0.f,0.f,0.f,0.f};

  const int ko = g*8;                 // K-offset within 32-ci chunk (granule g)
  const int wOff = (coBase + l15)*32 + ko;   // lane-constant part of weight index

  for (int cc = 0; cc < 4; ++cc) {
    __syncthreads();
    const unsigned short* xcc = xT + ((size_t)(bb*4 + cc))*NPIX*32;
    if (interior) {
      #pragma unroll
      for (int k = 0; k < 8; ++k) {
        int blk = k*4 + wv;            // 64-granule block, wave-uniform
        int idx = blk*64 + l;          // granule id
        int p = idx >> 2, i = idx & 3;
        int pc = p < 484 ? p : 483;
        int py = pc / 22, px = pc - py*22;
        int gpix = (y0-3+py)*128 + (x0-3+px);
        int sg = i ^ ((p >> 1) & 3);
        const unsigned short* srcp = xcc + (size_t)gpix*32 + sg*8;
        gload_lds16(srcp, (char*)sX + blk*1024);
      }
    } else {
      #pragma unroll
      for (int k = 0; k < 8; ++k) {
        int idx = k*256 + tid;
        int p = idx >> 2, i = idx & 3;
        u16x8 v = {0,0,0,0,0,0,0,0};
        if (p < 484) {
          int py = p / 22, px = p - py*22;
          int gy = y0-3+py, gx = x0-3+px;
          if ((unsigned)gy < 128u && (unsigned)gx < 128u) {
            int sg = i ^ ((p >> 1) & 3);
            v = *(const u16x8*)(xcc + (size_t)(gy*128+gx)*32 + sg*8);
          }
        }
        *(u16x8*)((char*)sX + idx*16) = v;
      }
    }

    // all 9 taps' weight frags for this chunk -> registers (issued pre-barrier;
    // the barrier's vmcnt drain covers their latency alongside the staging)
    bf16x8 aw[9][2];
    {
      const unsigned short* wcc = wP + cc*18432 + wOff;
      #pragma unroll
      for (int tap = 0; tap < 9; ++tap) {
        aw[tap][0] = *reinterpret_cast<const bf16x8*>(wcc + tap*2048);
        aw[tap][1] = *reinterpret_cast<const bf16x8*>(wcc + tap*2048 + 512);
      }
    }
    __syncthreads();

    #pragma unroll
    for (int tap = 0; tap < 9; ++tap) {
      int dy = (tap/3)*3, dx = (tap - (tap/3)*3)*3;
      bf16x8 b[4];
      #pragma unroll
      for (int n = 0; n < 4; ++n) {
        int p = (wv*4 + n + dy)*22 + l15 + dx;
        b[n] = *reinterpret_cast<const bf16x8*>(&sX[p*32 + ((g ^ ((p >> 1) & 3)) << 3)]);
      }
      #pragma unroll
      for (int m = 0; m < 2; ++m)
        #pragma unroll
        for (int n = 0; n < 4; ++n)
          acc[m][n] = __builtin_amdgcn_mfma_f32_16x16x32_bf16(aw[tap][m], b[n], acc[m][n], 0, 0, 0);
    }
  }

  // epilogue: BN + GELU + feat store (bf16) + fused u partials (this half's 32 couts)
  float up[4][4];   // [n][m2]
  #pragma unroll
  for (int n=0;n<4;++n)
    #pragma unroll
    for (int m2=0;m2<4;++m2) up[n][m2] = 0.f;

  #pragma unroll
  for (int m = 0; m < 2; ++m) {
    #pragma unroll
    for (int r = 0; r < 4; ++r) {
      int co = coBase + m*16 + g*4 + r;
      float sc = bg[co] * rsqrtf(bv[co] + 1e-5f);
      float sh = bbeta[co] - bm[co]*sc;
      float wv4[4];
      #pragma unroll
      for (int m2 = 0; m2 < 4; ++m2) wv4[m2] = w1s[m2*64 + co];
      #pragma unroll
      for (int n = 0; n < 4; ++n) {
        int py = wv*4 + n;
        float v = gelu_exact(acc[m][n][r]*sc + sh);
        feat[((size_t)(bb*CDN + co)*128 + (y0+py))*128 + x0 + l15] = f2bf(v);
        #pragma unroll
        for (int m2 = 0; m2 < 4; ++m2) up[n][m2] += wv4[m2]*v;
      }
    }
  }
  #pragma unroll
  for (int n=0;n<4;++n)
    #pragma unroll
    for (int m2=0;m2<4;++m2) {
      up[n][m2] += __shfl_xor(up[n][m2], 16, 64);
      up[n][m2] += __shfl_xor(up[n][m2], 32, 64);
    }
  if (g == 0) {
    #pragma unroll
    for (int n = 0; n < 4; ++n) {
      int py = y0 + wv*4 + n;
      #pragma unroll
      for (int m2 = 0; m2 < 4; ++m2)
        u[((size_t)((bb*2 + half)*4 + m2))*NPIX + py*128 + x0 + l15] = up[n][m2];
    }
  }
}

// Mid-pipeline combo (512 threads):
//   blocks [0,512):   attn1 partial Gram (feat-dependent)
//   blocks [512,544): ufft 2-D FFT of u -> mid (u-dependent; only 32 blocks, fills idle CUs)
__global__ __launch_bounds__(512) void k_mid(const unsigned short* __restrict__ feat, float* __restrict__ part,
    const float* __restrict__ u, const float* __restrict__ b1,
    const float* __restrict__ gg, const float* __restrict__ gbeta,
    const float* __restrict__ gm, const float* __restrict__ gv,
    float* __restrict__ mid){
  __shared__ c2 T[64*129];   // 66,048 B (attn1 path reuses as float scratch)
  int tid = threadIdx.x, wv = tid >> 6, t = tid & 63;

  if (blockIdx.x < 512) {
    // ---------------- attn1 path ----------------
    int bh = blockIdx.x >> 3, ck = blockIdx.x & 7;
    int b = bh >> 3, h = bh & 7;
    const unsigned short* f = feat + (size_t)(b*CDN + h*HDIM)*NPIX;
    float acc[36];
    #pragma unroll
    for (int i=0;i<36;++i) acc[i]=0.f;
    for (int p = ck*2048 + tid; p < (ck+1)*2048; p += 512) {
      float v[8];
      #pragma unroll
      for (int d=0; d<8; ++d) v[d] = bf2f(f[d*NPIX + p]);
      int i = 0;
      #pragma unroll
      for (int d=0; d<8; ++d)
        #pragma unroll
        for (int e=0; e<=d; ++e) acc[i++] += v[d]*v[e];
    }
    #pragma unroll
    for (int i=0;i<36;++i)
      #pragma unroll
      for (int off=32; off; off>>=1) acc[i] += __shfl_xor(acc[i], off, 64);
    float* red = (float*)T;    // [8][36]
    if (t == 0) {
      #pragma unroll
      for (int i=0;i<36;++i) red[wv*36 + i] = acc[i];
    }
    __syncthreads();
    if (tid < 36) {
      float s = 0.f;
      #pragma unroll
      for (int k = 0; k < 8; ++k) s += red[k*36 + tid];
      part[(bh*8+ck)*36 + tid] = s;
    }
    return;
  }

  // ---------------- ufft path ----------------
  int ib = blockIdx.x - 512;       // [0,32)
  int b = ib >> 2, m = ib & 3;
  Tw w; tw_init(w, t);
  const float* src0 = u + (size_t)((b*2+0)*4+m)*NPIX;
  const float* src1 = u + (size_t)((b*2+1)*4+m)*NPIX;
  c2 ra[16], rb[16];
  #pragma unroll
  for (int i = 0; i < 16; ++i) {
    int y = wv*16 + i;
    ra[i] = {src0[y*128 + t] + src1[y*128 + t], 0.f};
    rb[i] = {src0[y*128 + t + 64] + src1[y*128 + t + 64], 0.f};
  }
  #pragma unroll
  for (int i = 0; i < 16; ++i) fft128_fwd(ra[i], rb[i], t, w);
  c2 ca[16], cb[16];
  if (wv < 4) {
    #pragma unroll
    for (int i = 0; i < 16; ++i) {
      int y = wv*16 + i;
      T[y*129 + t] = ra[i]; T[y*129 + t + 64] = rb[i];
    }
  }
  __syncthreads();
  #pragma unroll
  for (int i = 0; i < 16; ++i) ca[i] = T[t*129 + wv*16 + i];
  __syncthreads();
  if (wv >= 4) {
    #pragma unroll
    for (int i = 0; i < 16; ++i) {
      int y = (wv-4)*16 + i;
      T[y*129 + t] = ra[i]; T[y*129 + t + 64] = rb[i];
    }
  }
  __syncthreads();
  #pragma unroll
  for (int i = 0; i < 16; ++i) cb[i] = T[t*129 + wv*16 + i];
  #pragma unroll
  for (int i = 0; i < 16; ++i) fft128_fwd(ca[i], cb[i], t, w);
  float sc = gg[m]*rsqrtf(gv[m]+1e-5f);
  float sh = gbeta[m] - gm[m]*sc;
  float bb1 = b1[m];
  float* md = mid + (size_t)(b*4+m)*NPIX;
  #pragma unroll
  for (int i = 0; i < 16; ++i) {
    int kx = wv*16 + i;
    md[kx*128 + t]      = gelu_exact((ca[i].x + bb1)*sc + sh);
    md[kx*128 + t + 64] = gelu_exact((cb[i].x + bb1)*sc + sh);
  }
}

// Tail combo (1024 threads):
//   blocks [0,128):    gmap (mid-dependent) -> gPack
//   blocks [128,1152): outf attention epilogue (part-dependent) -> out ch 0..63
__global__ __launch_bounds__(1024) void k_tail(const float* __restrict__ mid, const float* __restrict__ w2,
    const float* __restrict__ b2, unsigned* __restrict__ gPack,
    const unsigned short* __restrict__ feat, const float* __restrict__ part,
    const float* __restrict__ tau, const float* __restrict__ x, float* __restrict__ out){
  __shared__ float S[384];
  int tid = threadIdx.x;

  if (blockIdx.x < 128) {
    // ---------------- gmap path ----------------
    if (tid < 256) S[tid] = w2[tid];
    else if (tid < 320) S[tid] = b2[tid - 256];
    __syncthreads();
    int b = blockIdx.x >> 4;
    int k = (blockIdx.x & 15)*1024 + tid;
    const float* md = mid + (size_t)b*4*NPIX + k;
    float m0 = md[0], m1 = md[NPIX], m2 = md[2*NPIX], m3 = md[3*NPIX];
    unsigned* gp = gPack + (size_t)b*32*NPIX + k;
    #pragma unroll 8
    for (int cp = 0; cp < 32; ++cp) {
      float slo = S[256+cp]    + S[cp*4]*m0      + S[cp*4+1]*m1      + S[cp*4+2]*m2      + S[cp*4+3]*m3;
      float shi = S[256+cp+32] + S[(cp+32)*4]*m0 + S[(cp+32)*4+1]*m1 + S[(cp+32)*4+2]*m2 + S[(cp+32)*4+3]*m3;
      slo = 1.f/(1.f+expf(-slo));
      shi = 1.f/(1.f+expf(-shi));
      gp[(size_t)cp*NPIX] = ((unsigned)f2bf(shi) << 16) | (unsigned)f2bf(slo);
    }
    return;
  }

  // ---------------- outf path ----------------
  int idx = blockIdx.x - 128;      // [0,1024)
  int bh = idx >> 4;
  int b = bh >> 3, h = bh & 7;
  int p = (idx & 15)*1024 + tid;
  if (tid < 36) {
    float s = 0.f;
    #pragma unroll
    for (int k = 0; k < 8; ++k) s += part[(bh*8+k)*36 + tid];
    S[64 + tid] = s;
  }
  __syncthreads();
  if (tid == 0) {
    float G[8][8];
    int c2i=0;
    for (int d=0;d<8;++d) for(int e=0;e<=d;++e){
      float s = S[64 + c2i]; G[d][e]=s; G[e][d]=s; ++c2i;
    }
    float nrm[8];
    for (int d=0;d<8;++d) nrm[d] = sqrtf(16384.f*G[d][d] + 1e-6f);
    float tv = tau[h];
    for (int d=0;d<8;++d) {
      float row[8]; float mx = -1e30f;
      for (int e=0;e<8;++e){ row[e] = tv*16384.f*G[d][e]/(nrm[d]*nrm[e]); mx = fmaxf(mx,row[e]); }
      float s=0.f;
      for (int e=0;e<8;++e){ row[e] = expf(row[e]-mx); s += row[e]; }
      for (int e=0;e<8;++e) S[d*8+e] = row[e]/s;
    }
  }
  __syncthreads();
  const unsigned short* f = feat + (size_t)(b*CDN + h*HDIM)*NPIX;
  float v[8];
  #pragma unroll
  for (int e=0;e<8;++e) v[e] = bf2f(f[e*NPIX + p]);
  float im = 0.f;
  #pragma unroll
  for (int e=0;e<8;++e) im += v[e];
  im *= 0.125f;
  #pragma unroll
  for (int d=0;d<8;++d){
    float re = 0.f;
    #pragma unroll
    for (int e=0;e<8;++e) re += S[d*8+e]*v[e];
    size_t o = ((size_t)(b*CIN + h*HDIM + d))*NPIX + p;
    out[o] = sqrtf(re*re + im*im) + x[o];
  }
}

// Hermitian-packed fused gate branch, 1024 threads. Two half-image column
// passes through T[128][65] (66.5KB), sigma-closed per half.
__global__ __launch_bounds__(1024)
void k_fused(const unsigned short* __restrict__ feat, const unsigned* __restrict__ gPack,
             const float* __restrict__ x, float* __restrict__ out){
  __shared__ c2 T[128*65];   // 66,560 B
  int ib = blockIdx.x;       // b*32 + c, c in [0,32)
  int b = ib >> 5, c = ib & 31;
  int tid = threadIdx.x, wv = tid >> 6, t = tid & 63;
  Tw w; tw_init(w, t);
  int ta = __brev((64 - (__brev(t) >> 26)) & 63) >> 26;   // ky-partner lane for a-slots
  const unsigned short* srcA = feat + (size_t)(b*CDN + c)*NPIX;
  const unsigned short* srcB = feat + (size_t)(b*CDN + c + 32)*NPIX;
  const unsigned* gp = gPack + (size_t)(b*32 + c)*NPIX;

  c2 ra[8], rb[8];
  #pragma unroll
  for (int i = 0; i < 8; ++i) {
    int y = wv*8 + i;
    ra[i] = {bf2f(srcA[y*128 + t]),      bf2f(srcB[y*128 + t])};
    rb[i] = {bf2f(srcA[y*128 + t + 64]), bf2f(srcB[y*128 + t + 64])};
  }
  #pragma unroll
  for (int i = 0; i < 8; ++i) fft128_fwd(ra[i], rb[i], t, w);

  #define GUN(w_, lo_, hi_) float lo_ = __uint_as_float((w_) << 16); float hi_ = __uint_as_float((w_) & 0xffff0000u);
  #define CPAIR(I, J) { \
    GUN(gwa[I], g1aI, g2aI); GUN(gwb[I], g1bI, g2bI); \
    GUN(gwa[J], g1aJ, g2aJ); GUN(gwb[J], g1bJ, g2bJ); \
    c2 paI = { __shfl(ca[J].x, ta, 64), -__shfl(ca[J].y, ta, 64) }; \
    c2 paJ = { __shfl(ca[I].x, ta, 64), -__shfl(ca[I].y, ta, 64) }; \
    c2 pbI = { __shfl_xor(cb[J].x, 63, 64), -__shfl_xor(cb[J].y, 63, 64) }; \
    c2 pbJ = { __shfl_xor(cb[I].x, 63, 64), -__shfl_xor(cb[I].y, 63, 64) }; \
    float gsaI=0.5f*(g1aI+g2aI), gdaI=0.5f*(g1aI-g2aI); \
    float gsaJ=0.5f*(g1aJ+g2aJ), gdaJ=0.5f*(g1aJ-g2aJ); \
    float gsbI=0.5f*(g1bI+g2bI), gdbI=0.5f*(g1bI-g2bI); \
    float gsbJ=0.5f*(g1bJ+g2bJ), gdbJ=0.5f*(g1bJ-g2bJ); \
    ca[I] = { gsaI*ca[I].x + gdaI*paI.x, gsaI*ca[I].y + gdaI*paI.y }; \
    ca[J] = { gsaJ*ca[J].x + gdaJ*paJ.x, gsaJ*ca[J].y + gdaJ*paJ.y }; \
    cb[I] = { gsbI*cb[I].x + gdbI*pbI.x, gsbI*cb[I].y + gdbI*pbI.y }; \
    cb[J] = { gsbJ*cb[J].x + gdbJ*pbJ.x, gsbJ*cb[J].y + gdbJ*pbJ.y }; \
  }
  #define CSELF(I) { \
    GUN(gwa[I], g1aI, g2aI); GUN(gwb[I], g1bI, g2bI); \
    c2 paI = { __shfl(ca[I].x, ta, 64), -__shfl(ca[I].y, ta, 64) }; \
    c2 pbI = { __shfl_xor(cb[I].x, 63, 64), -__shfl_xor(cb[I].y, 63, 64) }; \
    float gsaI=0.5f*(g1aI+g2aI), gdaI=0.5f*(g1aI-g2aI); \
    float gsbI=0.5f*(g1bI+g2bI), gdbI=0.5f*(g1bI-g2bI); \
    ca[I] = { gsaI*ca[I].x + gdaI*paI.x, gsaI*ca[I].y + gdaI*paI.y }; \
    cb[I] = { gsbI*cb[I].x + gdbI*pbI.x, gsbI*cb[I].y + gdbI*pbI.y }; \
  }

  // ---- PASS A: columns 0..63 ----
  #pragma unroll
  for (int i = 0; i < 8; ++i) T[(wv*8 + i)*65 + t] = ra[i];
  __syncthreads();
  {
    int s0 = cmapA(wv,0), s1 = cmapA(wv,1), s2 = cmapA(wv,2), s3 = cmapA(wv,3);
    c2 ca[4], cb[4];
    ca[0]=T[t*65+s0]; ca[1]=T[t*65+s1]; ca[2]=T[t*65+s2]; ca[3]=T[t*65+s3];
    cb[0]=T[(t+64)*65+s0]; cb[1]=T[(t+64)*65+s1]; cb[2]=T[(t+64)*65+s2]; cb[3]=T[(t+64)*65+s3];
    unsigned gwa[4], gwb[4];
    gwa[0]=gp[s0*128+t]; gwa[1]=gp[s1*128+t]; gwa[2]=gp[s2*128+t]; gwa[3]=gp[s3*128+t];
    gwb[0]=gp[s0*128+64+t]; gwb[1]=gp[s1*128+64+t]; gwb[2]=gp[s2*128+64+t]; gwb[3]=gp[s3*128+64+t];
    #pragma unroll
    for (int j = 0; j < 4; ++j) fft128_fwd(ca[j], cb[j], t, w);
    if (wv == 0) { CSELF(0); CSELF(1); CPAIR(2,3); }
    else         { CPAIR(0,3); CPAIR(1,2); }
    #pragma unroll
    for (int j = 0; j < 4; ++j) fft128_inv(ca[j], cb[j], t, w);
    __syncthreads();   // everyone done reading their cols before write-back
    T[t*65+s0]=ca[0]; T[t*65+s1]=ca[1]; T[t*65+s2]=ca[2]; T[t*65+s3]=ca[3];
    T[(t+64)*65+s0]=cb[0]; T[(t+64)*65+s1]=cb[1]; T[(t+64)*65+s2]=cb[2]; T[(t+64)*65+s3]=cb[3];
  }
  __syncthreads();
  #pragma unroll
  for (int i = 0; i < 8; ++i) ra[i] = T[(wv*8 + i)*65 + t];
  __syncthreads();

  // ---- PASS B: columns 64..127 (stored at col-64) ----
  #pragma unroll
  for (int i = 0; i < 8; ++i) T[(wv*8 + i)*65 + t] = rb[i];
  __syncthreads();
  {
    int s0 = cmapB(wv,0), s1 = cmapB(wv,1), s2 = cmapB(wv,2), s3 = cmapB(wv,3);
    c2 ca[4], cb[4];
    ca[0]=T[t*65+s0]; ca[1]=T[t*65+s1]; ca[2]=T[t*65+s2]; ca[3]=T[t*65+s3];
    cb[0]=T[(t+64)*65+s0]; cb[1]=T[(t+64)*65+s1]; cb[2]=T[(t+64)*65+s2]; cb[3]=T[(t+64)*65+s3];
    unsigned gwa[4], gwb[4];
    gwa[0]=gp[(64+s0)*128+t]; gwa[1]=gp[(64+s1)*128+t]; gwa[2]=gp[(64+s2)*128+t]; gwa[3]=gp[(64+s3)*128+t];
    gwb[0]=gp[(64+s0)*128+64+t]; gwb[1]=gp[(64+s1)*128+64+t]; gwb[2]=gp[(64+s2)*128+64+t]; gwb[3]=gp[(64+s3)*128+64+t];
    #pragma unroll
    for (int j = 0; j < 4; ++j) fft128_fwd(ca[j], cb[j], t, w);
    CPAIR(0,3); CPAIR(1,2);
    #pragma unroll
    for (int j = 0; j < 4; ++j) fft128_inv(ca[j], cb[j], t, w);
    __syncthreads();
    T[t*65+s0]=ca[0]; T[t*65+s1]=ca[1]; T[t*65+s2]=ca[2]; T[t*65+s3]=ca[3];
    T[(t+64)*65+s0]=cb[0]; T[(t+64)*65+s1]=cb[1]; T[(t+64)*65+s2]=cb[2]; T[(t+64)*65+s3]=cb[3];
  }
  __syncthreads();
  #pragma unroll
  for (int i = 0; i < 8; ++i) rb[i] = T[(wv*8 + i)*65 + t];
  #undef CPAIR
  #undef CSELF
  #undef GUN

  // inverse row FFT + abs + residual (out1 = Re -> ch 64+c, out2 = Im -> ch 96+c)
  #pragma unroll
  for (int i = 0; i < 8; ++i) fft128_inv(ra[i], rb[i], t, w);
  const float* xr1 = x + ((size_t)(b*CIN + 64 + c))*NPIX;
  const float* xr2 = x + ((size_t)(b*CIN + 96 + c))*NPIX;
  float* o1 = out + ((size_t)(b*CIN + 64 + c))*NPIX;
  float* o2 = out + ((size_t)(b*CIN + 96 + c))*NPIX;
  const float s = 1.f/16384.f;
  #pragma unroll
  for (int i = 0; i < 8; ++i) {
    int y = wv*8 + i;
    o1[y*128 + t]      = fabsf(ra[i].x)*s + xr1[y*128 + t];
    o1[y*128 + t + 64] = fabsf(rb[i].x)*s + xr1[y*128 + t + 64];
    o2[y*128 + t]      = fabsf(ra[i].y)*s + xr2[y*128 + t];
    o2[y*128 + t + 64] = fabsf(rb[i].y)*s + xr2[y*128 + t + 64];
  }
}

extern "C" void kernel_launch(void* const* d_in, const int* in_sizes, int n_in,
                              void* d_out, int out_size, void* d_ws, size_t ws_size,
                              hipStream_t stream){
  const float* x      = (const float*)d_in[0];
  const float* conv_w = (const float*)d_in[1];
  const float* bn1_g  = (const float*)d_in[2];
  const float* bn1_b  = (const float*)d_in[3];
  const float* bn1_m  = (const float*)d_in[4];
  const float* bn1_v  = (const float*)d_in[5];
  const float* cg1_w  = (const float*)d_in[6];
  const float* cg1_b  = (const float*)d_in[7];
  const float* cgbn_g = (const float*)d_in[8];
  const float* cgbn_b = (const float*)d_in[9];
  const float* cgbn_m = (const float*)d_in[10];
  const float* cgbn_v = (const float*)d_in[11];
  const float* cg2_w  = (const float*)d_in[12];
  const float* cg2_b  = (const float*)d_in[13];
  const float* tau    = (const float*)d_in[14];
  float* out = (float*)d_out;

  char* ws = (char*)d_ws;
  unsigned short* feat  = (unsigned short*)ws;                  // 16,777,216 B (bf16)
  unsigned short* xT    = (unsigned short*)(ws + 33554432);     // 33,554,432 B (dead after k_conv)
  unsigned*       gPack = (unsigned*)(ws + 33554432);           // 16,777,216 B, aliases xT (safe)
  float*          u     = (float*)(ws + 67108864);              // 4,194,304 B ([b][half][m][NPIX])
  float*          mid   = (float*)(ws + 71303168);              // 2,097,152 B
  unsigned short* wPack = (unsigned short*)(ws + 73400320);     // 147,456 B
  float*          part  = (float*)(ws + 73547776);              // 73,728 B

  k_prep<<<800, 256, 0, stream>>>(x, xT, conv_w, wPack);
  k_conv<<<dim3(16,8,NB), 256, 0, stream>>>(xT, wPack, bn1_g, bn1_b, bn1_m, bn1_v, cg1_w, feat, u);
  k_mid<<<544, 512, 0, stream>>>(feat, part, u, cg1_b, cgbn_g, cgbn_b, cgbn_m, cgbn_v, mid);
  k_tail<<<1152, 1024, 0, stream>>>(mid, cg2_w, cg2_b, gPack, feat, part, tau, x, out);
  k_fused<<<NB*32, 1024, 0, stream>>>(feat, gPack, x, out);
}